// Round 2
// baseline (1316.542 us; speedup 1.0000x reference)
//
#include <hip/hip_runtime.h>
#include <hip/hip_bf16.h>
#include <cstdint>
#include <cstddef>

#define EPS_IN 1e-5f

// ---------------------------------------------------------------------------
// Instance-norm + residual: y = (x - mean) * rsqrt(var + eps) + x
// One block (256 threads) per channel.
// ---------------------------------------------------------------------------
__global__ void inorm_res_kernel(const float* __restrict__ in, float* __restrict__ out, int HW) {
    int c = blockIdx.x;
    const float* src = in + (size_t)c * HW;
    float* dst = out + (size_t)c * HW;
    float s = 0.f, q = 0.f;
    for (int i = threadIdx.x; i < HW; i += blockDim.x) {
        float v = src[i];
        s += v; q += v * v;
    }
#pragma unroll
    for (int off = 32; off >= 1; off >>= 1) {
        s += __shfl_down(s, off, 64);
        q += __shfl_down(q, off, 64);
    }
    __shared__ float ss[4], sq[4], mr[2];
    int wave = threadIdx.x >> 6;
    if ((threadIdx.x & 63) == 0) { ss[wave] = s; sq[wave] = q; }
    __syncthreads();
    if (threadIdx.x == 0) {
        float ts = ss[0] + ss[1] + ss[2] + ss[3];
        float tq = sq[0] + sq[1] + sq[2] + sq[3];
        float m = ts / (float)HW;
        float var = tq / (float)HW - m * m;
        mr[0] = m;
        mr[1] = rsqrtf(var + EPS_IN);
    }
    __syncthreads();
    float m = mr[0], r = mr[1];
    for (int i = threadIdx.x; i < HW; i += blockDim.x) {
        float v = src[i];
        dst[i] = (v - m) * r + v;   // in-place safe: each i touched by exactly one thread
    }
}

// ---------------------------------------------------------------------------
// Direct 3x3 SAME conv, NCHW, weights (O, Cin, 3, 3) fp32.
// Block = 256 pixels of one group of OBLK output channels; weights in LDS.
// ---------------------------------------------------------------------------
template <int OBLK>
__global__ void conv3x3_kernel(const float* __restrict__ in, const float* __restrict__ w,
                               const float* __restrict__ bias, float* __restrict__ out,
                               int Cin, int H, int W) {
    extern __shared__ float wsm[];   // [Cin][9][OBLK]
    int o0 = blockIdx.y * OBLK;
    int n = Cin * 9 * OBLK;
    for (int t = threadIdx.x; t < n; t += blockDim.x) {
        int ob = t % OBLK;
        int tap = (t / OBLK) % 9;
        int c = t / (9 * OBLK);
        wsm[t] = w[((size_t)(o0 + ob) * Cin + c) * 9 + tap];
    }
    __syncthreads();
    int HW = H * W;
    int pix = blockIdx.x * blockDim.x + threadIdx.x;
    if (pix >= HW) return;
    int y = pix / W, x = pix % W;
    float acc[OBLK];
#pragma unroll
    for (int ob = 0; ob < OBLK; ob++) acc[ob] = bias[o0 + ob];
    bool xl = (x > 0), xr = (x < W - 1);
    for (int c = 0; c < Cin; c++) {
        const float* base = in + (size_t)c * HW + pix;
        const float* wc = wsm + (size_t)c * 9 * OBLK;
#pragma unroll
        for (int dy = 0; dy < 3; dy++) {
            int yy = y + dy - 1;
            if (yy < 0 || yy >= H) continue;
            const float* row = base + (dy - 1) * W;
            float v0 = xl ? row[-1] : 0.f;
            float v1 = row[0];
            float v2 = xr ? row[1] : 0.f;
#pragma unroll
            for (int ob = 0; ob < OBLK; ob++) {
                acc[ob] += v0 * wc[(dy * 3 + 0) * OBLK + ob];
                acc[ob] += v1 * wc[(dy * 3 + 1) * OBLK + ob];
                acc[ob] += v2 * wc[(dy * 3 + 2) * OBLK + ob];
            }
        }
    }
#pragma unroll
    for (int ob = 0; ob < OBLK; ob++)
        out[(size_t)(o0 + ob) * HW + pix] = acc[ob];
}

// ---------------------------------------------------------------------------
// PAC adaptive kernel weights: kk[tap][y][x] = exp(-0.5 * sum_c (gp - g)^2)
// gp = guide zero-padded by 1, shifted by (i-1, j-1).
// ---------------------------------------------------------------------------
__global__ void kk_kernel(const float* __restrict__ g, float* __restrict__ kkout,
                          int Cg, int H, int W) {
    int tap = blockIdx.y;
    int i = tap / 3, j = tap % 3;
    int HW = H * W;
    int pix = blockIdx.x * blockDim.x + threadIdx.x;
    if (pix >= HW) return;
    int y = pix / W, x = pix % W;
    int gy = y + i - 1, gx = x + j - 1;
    bool inb = (gy >= 0 && gy < H && gx >= 0 && gx < W);
    const float* pn = g + (inb ? ((size_t)gy * W + gx) : 0);
    float s = 0.f;
    for (int c = 0; c < Cg; c++) {
        float a = inb ? pn[(size_t)c * HW] : 0.f;
        float d = a - g[(size_t)c * HW + pix];
        s += d * d;
    }
    kkout[(size_t)tap * HW + pix] = __expf(-0.5f * s);
}

// ---------------------------------------------------------------------------
// PAC transposed conv, stride 2, k=3, pad=1, out_pad=1.
// Output pixel (y,x): valid taps (i,j) have (y+i) odd && (x+j) odd and
// ym=(y+i-1)/2 < Hi, xm=(x+j-1)/2 < Wi. out[o,y,x] = b[o] +
//   sum_taps kk[tap,y,x] * sum_c x[c,ym,xm] * w[c,o,i,j]
// blockIdx.z selects parity class (ry,rx) so tap validity is wave-uniform.
// Weights (C, O, 3, 3) fp32; per-block slice staged in LDS.
// ---------------------------------------------------------------------------
template <int OBLK>
__global__ void pac_kernel(const float* __restrict__ xin, const float* __restrict__ kk,
                           const float* __restrict__ w, const float* __restrict__ bias,
                           float* __restrict__ out,
                           int C, int O, int Hi, int Wi, int Ho, int Wo) {
    extern __shared__ float wsm[];   // [C][9][OBLK]
    int o0 = blockIdx.y * OBLK;
    int n = C * 9 * OBLK;
    for (int t = threadIdx.x; t < n; t += blockDim.x) {
        int ob = t % OBLK;
        int tap = (t / OBLK) % 9;
        int c = t / (9 * OBLK);
        wsm[t] = w[((size_t)c * O + (o0 + ob)) * 9 + tap];
    }
    __syncthreads();
    int ry = (blockIdx.z >> 1) & 1, rx = blockIdx.z & 1;
    int Wh = Wo >> 1;
    int p = blockIdx.x * blockDim.x + threadIdx.x;
    int ys = p / Wh, xs = p % Wh;
    int y = 2 * ys + ry, x = 2 * xs + rx;
    int HoWo = Ho * Wo, HiWi = Hi * Wi;
    int pix = y * Wo + x;
    float acc[OBLK];
#pragma unroll
    for (int ob = 0; ob < OBLK; ob++) acc[ob] = bias[o0 + ob];
#pragma unroll
    for (int i = 0; i < 3; i++) {
        int a = y + i;
        if (!(a & 1)) continue;
        int ym = (a - 1) >> 1;
        if (ym >= Hi) continue;
#pragma unroll
        for (int j = 0; j < 3; j++) {
            int bcol = x + j;
            if (!(bcol & 1)) continue;
            int xm = (bcol - 1) >> 1;
            if (xm >= Wi) continue;
            int tap = i * 3 + j;
            float kv = kk[(size_t)tap * HoWo + pix];
            const float* xb = xin + (size_t)ym * Wi + xm;
            const float* wb = wsm + tap * OBLK;
            float dot[OBLK];
#pragma unroll
            for (int ob = 0; ob < OBLK; ob++) dot[ob] = 0.f;
            for (int c = 0; c < C; c++) {
                float xv = xb[(size_t)c * HiWi];
#pragma unroll
                for (int ob = 0; ob < OBLK; ob++) dot[ob] += xv * wb[(size_t)c * 9 * OBLK + ob];
            }
#pragma unroll
            for (int ob = 0; ob < OBLK; ob++) acc[ob] += kv * dot[ob];
        }
    }
#pragma unroll
    for (int ob = 0; ob < OBLK; ob++)
        out[(size_t)(o0 + ob) * HoWo + pix] = acc[ob];
}

// ---------------------------------------------------------------------------
extern "C" void kernel_launch(void* const* d_in, const int* in_sizes, int n_in,
                              void* d_out, int out_size, void* d_ws, size_t ws_size,
                              hipStream_t stream) {
    const float* x      = (const float*)d_in[0];   // (256,64,64)
    const float* ef2    = (const float*)d_in[1];   // (128,128,128)
    const float* ef1    = (const float*)d_in[2];   // (64,256,256)
    const float* w_adj2 = (const float*)d_in[3];   // (256,128,3,3)
    const float* b_adj2 = (const float*)d_in[4];
    const float* w_adj1 = (const float*)d_in[5];   // (128,64,3,3)
    const float* b_adj1 = (const float*)d_in[6];
    const float* w_p16  = (const float*)d_in[7];   // (256,128,3,3)  (Cin,O,kh,kw)
    const float* b_p16  = (const float*)d_in[8];
    const float* w_p20  = (const float*)d_in[9];   // (128,64,3,3)
    const float* b_p20  = (const float*)d_in[10];
    const float* w_out  = (const float*)d_in[11];  // (3,64,3,3)
    const float* b_out  = (const float*)d_in[12];
    float* out = (float*)d_out;                    // (3,256,256)

    // Workspace layout (floats). Guide buffers computed FIRST, then their
    // regions are reused for the x-path intermediates (peak ~57.5 MB).
    float* ws  = (float*)d_ws;
    float* bx0 = ws;                     // 1,048,576   x after 2 inorms      [0 .. 1.05M)
    float* bk2 = ws + 1048576;           // 147,456     kk for pac16
    float* bk1 = ws + 1196032;           // 589,824     kk for pac20
    float* bg2 = ws + 1785856;           // 4,194,304   guide2 (dead after kk2)
    float* bg1 = ws + 5980160;           // 8,388,608   guide1 (dead after kk1)
    float* bx1 = bg2;                    // 2,097,152   aliases bg2 (dead)
    float* bx2 = bg1;                    // 4,194,304   aliases bg1 (dead)
    // peak = 14,368,768 floats = 57.5 MB

    // g2 = conv3x3(ef_lv2): 128 -> 256 @ 128x128
    conv3x3_kernel<4><<<dim3(64, 64), 256, 128 * 9 * 4 * sizeof(float), stream>>>(
        ef2, w_adj2, b_adj2, bg2, 128, 128, 128);
    // kk for pac16 (guide = g2, 256 ch, 128x128)
    kk_kernel<<<dim3(64, 9), 256, 0, stream>>>(bg2, bk2, 256, 128, 128);

    // g1 = conv3x3(ef_lv1): 64 -> 128 @ 256x256
    conv3x3_kernel<4><<<dim3(256, 32), 256, 64 * 9 * 4 * sizeof(float), stream>>>(
        ef1, w_adj1, b_adj1, bg1, 64, 256, 256);
    // kk for pac20 (guide = g1, 128 ch, 256x256)
    kk_kernel<<<dim3(256, 9), 256, 0, stream>>>(bg1, bk1, 128, 256, 256);

    // x-path: x = inorm(x)+x twice  (256, 64x64)
    inorm_res_kernel<<<256, 256, 0, stream>>>(x, bx0, 4096);
    inorm_res_kernel<<<256, 256, 0, stream>>>(bx0, bx0, 4096);

    // pac16: (256, 64x64) -> (128, 128x128)   [bx1 aliases dead bg2]
    pac_kernel<4><<<dim3(16, 32, 4), 256, 256 * 9 * 4 * sizeof(float), stream>>>(
        bx0, bk2, w_p16, b_p16, bx1, 256, 128, 64, 64, 128, 128);

    inorm_res_kernel<<<128, 256, 0, stream>>>(bx1, bx1, 16384);
    inorm_res_kernel<<<128, 256, 0, stream>>>(bx1, bx1, 16384);

    // pac20: (128, 128x128) -> (64, 256x256)  [bx2 aliases dead bg1]
    pac_kernel<4><<<dim3(64, 16, 4), 256, 128 * 9 * 4 * sizeof(float), stream>>>(
        bx1, bk1, w_p20, b_p20, bx2, 128, 64, 128, 128, 256, 256);

    inorm_res_kernel<<<64, 256, 0, stream>>>(bx2, bx2, 65536);
    inorm_res_kernel<<<64, 256, 0, stream>>>(bx2, bx2, 65536);

    // final conv: 64 -> 3 @ 256x256
    conv3x3_kernel<1><<<dim3(256, 3), 256, 64 * 9 * 1 * sizeof(float), stream>>>(
        bx2, w_out, b_out, out, 64, 256, 256);
}